// Round 1
// baseline (342.019 us; speedup 1.0000x reference)
//
#include <hip/hip_runtime.h>
#include <stdint.h>

// AM-softmax loss, fused on MI355X (gfx950).
//   xn = x/||x||;  wf = xn·W^T  (bf16 MFMA, 16x16x32);
//   per-row logsumexp over C classes with margin-adjusted label column;
//   out[0] = -mean(numer - logsumexp).
//
// Pipeline (all on `stream`, graph-capture safe):
//   prep_x        : normalize x rows -> bf16, padded K-stride 200 (819 KB ws)
//   prep_w        : W fp32 -> bf16, padded [CP][200] (40 MB ws) so each
//                   128-class B tile is one contiguous 51.2 KB image ->
//                   staged via global_load_lds dwordx4, padding preserved.
//   gemm_lse      : 128x128 output tile, full K=192 resident in LDS (B only;
//                   A frags straight from global, xn is L2-resident).
//                   Epilogue: exp(S*wf), 16-lane shuffle reduce, LDS rowsum,
//                   one global atomicAdd per row.
//   finalize_rows : fp32 target logit, margin swap, log.
//   reduce_loss   : -mean.
//
// Numerics: bf16 rounding -> |d(S*wf)| ~ 1e-2 per logit, zero-mean over 1e5
// summed exps -> log error ~1e-4, threshold is 0.37. No max-subtraction
// needed: |S*wf| <= ~21 worst case, sum ~3e5, fp32-safe.

constexpr int N  = 2048;
constexpr int D  = 192;
constexpr int C  = 100000;
constexpr int KP = 200;               // padded K stride (bf16): 400 B rows -> LDS bank stride 4
constexpr int CT = (C + 127) / 128;   // 782 column tiles
constexpr int CP = CT * 128;          // 100096 padded class count

#define S_SCALE 30.0f
#define MARGIN  0.2f

using short8 = __attribute__((ext_vector_type(8))) short;   // 8 bf16 (4 VGPRs)
using f32x4  = __attribute__((ext_vector_type(4))) float;   // MFMA C/D

typedef __attribute__((address_space(1))) const void GV;
typedef __attribute__((address_space(3))) void LV;

__device__ inline unsigned short f2bf(float f) {  // fp32 -> bf16 RNE
  unsigned int u = __float_as_uint(f);
  u += 0x7fffu + ((u >> 16) & 1u);
  return (unsigned short)(u >> 16);
}

// ---------------- prep: normalize x rows, convert to padded bf16 ----------
__global__ __launch_bounds__(256) void prep_x(const float* __restrict__ x,
                                              unsigned short* __restrict__ xnb) {
  const int row  = blockIdx.x * 4 + (threadIdx.x >> 6);
  const int lane = threadIdx.x & 63;
  const float* xr = x + (size_t)row * D;
  float v0 = xr[lane], v1 = xr[lane + 64], v2 = xr[lane + 128];
  float ss = v0 * v0 + v1 * v1 + v2 * v2;
#pragma unroll
  for (int off = 32; off > 0; off >>= 1) ss += __shfl_xor(ss, off, 64);
  const float inv = rsqrtf(ss);
  unsigned short* o = xnb + (size_t)row * KP;
  o[lane]       = f2bf(v0 * inv);
  o[lane + 64]  = f2bf(v1 * inv);
  o[lane + 128] = f2bf(v2 * inv);
  if (lane < KP - D) o[D + lane] = 0;
}

// ---------------- prep: W fp32 -> padded bf16 [CP][KP] --------------------
__global__ __launch_bounds__(256) void prep_w(const float* __restrict__ W,
                                              unsigned short* __restrict__ Wb) {
  const int row  = blockIdx.x * 4 + (threadIdx.x >> 6);
  const int lane = threadIdx.x & 63;
  unsigned short* o = Wb + (size_t)row * KP;
  if (row < C) {
    const float* wr = W + (size_t)row * D;
    o[lane]       = f2bf(wr[lane]);
    o[lane + 64]  = f2bf(wr[lane + 64]);
    o[lane + 128] = f2bf(wr[lane + 128]);
  } else {  // phantom padding classes: zero (masked in epilogue anyway)
    o[lane] = 0; o[lane + 64] = 0; o[lane + 128] = 0;
  }
  if (lane < KP - D) o[D + lane] = 0;
}

// ---------------- main fused GEMM + exp-rowsum ----------------------------
// grid = (CT, N/128); block = 256 (4 waves, 2x2 quadrants of 64x64).
template <bool PRECONV>
__global__ __launch_bounds__(256) void gemm_lse(
    const unsigned short* __restrict__ xnb,  // [N][KP] bf16
    const unsigned short* __restrict__ Wb,   // [CP][KP] bf16 (PRECONV)
    const float* __restrict__ Wf,            // [C][D] fp32 (!PRECONV fallback)
    float* __restrict__ sumexp) {            // [N] fp32, pre-zeroed
  __shared__ alignas(16) unsigned short Bs[128 * KP];  // 51.2 KB
  __shared__ float rowsum[128];

  const int tid    = threadIdx.x;
  const int colblk = blockIdx.x;
  const int rowblk = blockIdx.y;

  if (tid < 128) rowsum[tid] = 0.0f;

  if constexpr (PRECONV) {
    // B tile is a contiguous 51.2 KB padded image: flat DMA copy to LDS.
    const unsigned short* src = Wb + (size_t)colblk * 128 * KP;
    constexpr int CHUNKS = 128 * KP * 2 / 16;  // 3200 x 16B
#pragma unroll
    for (int i = 0; i < (CHUNKS + 255) / 256; ++i) {
      const int chunk = tid + i * 256;  // last iter: waves 0,1 only (fully active)
      if (chunk < CHUNKS) {
        __builtin_amdgcn_global_load_lds(
            (GV*)((const char*)src + (size_t)chunk * 16),
            (LV*)((char*)Bs + (size_t)chunk * 16), 16, 0, 0);
      }
    }
  } else {
    // Fallback: stage from fp32 W with inline convert (ws too small for Wb).
    const int r  = tid >> 1;
    const int h  = tid & 1;
    const int rg = colblk * 128 + r;
    unsigned short* dst = &Bs[r * KP + h * 96];
    if (rg < C) {
      const float4* src = (const float4*)(Wf + (size_t)rg * D + h * 96);
#pragma unroll
      for (int i = 0; i < 24; ++i) {
        float4 f = src[i];
        dst[i * 4 + 0] = f2bf(f.x);
        dst[i * 4 + 1] = f2bf(f.y);
        dst[i * 4 + 2] = f2bf(f.z);
        dst[i * 4 + 3] = f2bf(f.w);
      }
    } else {
#pragma unroll
      for (int i = 0; i < 96; ++i) dst[i] = 0;
    }
    if (h == 1) {
#pragma unroll
      for (int i = 0; i < KP - D; ++i) dst[96 + i] = 0;
    }
  }
  __syncthreads();

  const int lane = tid & 63;
  const int wave = tid >> 6;
  const int m    = lane & 15;   // A: row in 16-tile; B: col in 16-tile
  const int quad = lane >> 4;   // k base = quad*8; C/D row base = quad*4
  const int wr   = wave >> 1;   // row half (64)
  const int wc   = wave & 1;    // col half (64)

  const f32x4 zero4 = {0.0f, 0.0f, 0.0f, 0.0f};
  f32x4 acc[4][4];
#pragma unroll
  for (int a = 0; a < 4; ++a)
#pragma unroll
    for (int b = 0; b < 4; ++b) acc[a][b] = zero4;

  const unsigned short* aptr =
      xnb + (size_t)(rowblk * 128 + wr * 64 + m) * KP + quad * 8;
  const unsigned short* bptr = &Bs[(wc * 64 + m) * KP + quad * 8];

#pragma unroll
  for (int ks = 0; ks < 6; ++ks) {  // K = 6 * 32
    short8 af[4], bf[4];
#pragma unroll
    for (int t = 0; t < 4; ++t)
      af[t] = *(const short8*)(aptr + t * 16 * KP + ks * 32);
#pragma unroll
    for (int t = 0; t < 4; ++t)
      bf[t] = *(const short8*)(bptr + t * 16 * KP + ks * 32);
#pragma unroll
    for (int tr = 0; tr < 4; ++tr)
#pragma unroll
      for (int tc = 0; tc < 4; ++tc)
        acc[tr][tc] = __builtin_amdgcn_mfma_f32_16x16x32_bf16(
            af[tr], bf[tc], acc[tr][tc], 0, 0, 0);
  }

  // Epilogue: exp(S*wf), mask phantom cols, reduce over the 16 cols each
  // lane-group covers, accumulate per-row into LDS then global.
  const int colbase = colblk * 128 + wc * 64 + m;
#pragma unroll
  for (int tr = 0; tr < 4; ++tr) {
    float r0 = 0.f, r1 = 0.f, r2 = 0.f, r3 = 0.f;
#pragma unroll
    for (int tc = 0; tc < 4; ++tc) {
      if (colbase + tc * 16 < C) {
        r0 += __expf(S_SCALE * acc[tr][tc][0]);
        r1 += __expf(S_SCALE * acc[tr][tc][1]);
        r2 += __expf(S_SCALE * acc[tr][tc][2]);
        r3 += __expf(S_SCALE * acc[tr][tc][3]);
      }
    }
#pragma unroll
    for (int off = 1; off < 16; off <<= 1) {  // reduce across the 16 cols
      r0 += __shfl_xor(r0, off, 64);
      r1 += __shfl_xor(r1, off, 64);
      r2 += __shfl_xor(r2, off, 64);
      r3 += __shfl_xor(r3, off, 64);
    }
    if (m == 0) {
      const int rl = wr * 64 + tr * 16 + quad * 4;
      atomicAdd(&rowsum[rl + 0], r0);
      atomicAdd(&rowsum[rl + 1], r1);
      atomicAdd(&rowsum[rl + 2], r2);
      atomicAdd(&rowsum[rl + 3], r3);
    }
  }
  __syncthreads();
  if (tid < 128) atomicAdd(&sumexp[rowblk * 128 + tid], rowsum[tid]);
}

// ---------------- per-row finalize ---------------------------------------
__global__ __launch_bounds__(256) void finalize_rows(
    const float* __restrict__ x, const float* __restrict__ W,
    const int* __restrict__ label, const float* __restrict__ sumexp,
    float* __restrict__ Lrow) {
  const int row  = blockIdx.x * 4 + (threadIdx.x >> 6);
  const int lane = threadIdx.x & 63;
  const float* xr = x + (size_t)row * D;
  float v0 = xr[lane], v1 = xr[lane + 64], v2 = xr[lane + 128];
  float ss = v0 * v0 + v1 * v1 + v2 * v2;
  const int lab = label[row];
  const float* wr = W + (size_t)lab * D;
  float d = v0 * wr[lane] + v1 * wr[lane + 64] + v2 * wr[lane + 128];
#pragma unroll
  for (int off = 32; off > 0; off >>= 1) {
    ss += __shfl_xor(ss, off, 64);
    d  += __shfl_xor(d,  off, 64);
  }
  if (lane == 0) {
    const float tgt   = d * rsqrtf(ss);
    const float numer = S_SCALE * (tgt - MARGIN);
    // swap label column: remove its plain-logit exp, add margin-adjusted exp
    const float se = sumexp[row] - __expf(S_SCALE * tgt) + __expf(numer);
    Lrow[row] = numer - logf(se);
  }
}

__global__ __launch_bounds__(256) void reduce_loss(const float* __restrict__ Lrow,
                                                   float* __restrict__ out) {
  const int tid = threadIdx.x;
  float s = 0.0f;
  for (int i = tid; i < N; i += 256) s += Lrow[i];
#pragma unroll
  for (int off = 32; off > 0; off >>= 1) s += __shfl_xor(s, off, 64);
  __shared__ float part[4];
  if ((tid & 63) == 0) part[tid >> 6] = s;
  __syncthreads();
  if (tid == 0) out[0] = -(part[0] + part[1] + part[2] + part[3]) / (float)N;
}

// ---------------- host ----------------------------------------------------
extern "C" void kernel_launch(void* const* d_in, const int* in_sizes, int n_in,
                              void* d_out, int out_size, void* d_ws, size_t ws_size,
                              hipStream_t stream) {
  const float* x     = (const float*)d_in[0];
  const float* W     = (const float*)d_in[1];
  const int*   label = (const int*)d_in[2];
  float*       out   = (float*)d_out;

  char* ws = (char*)d_ws;
  const size_t wb_bytes = (size_t)CP * KP * 2;   // 40,038,400
  const size_t xb_bytes = (size_t)N * KP * 2;    //    819,200
  const size_t need_big = wb_bytes + xb_bytes + (size_t)2 * N * 4;
  const bool big = (ws_size >= need_big);

  size_t off = 0;
  unsigned short* Wb = nullptr;
  if (big) { Wb = (unsigned short*)(ws + off); off += wb_bytes; }
  unsigned short* xnb = (unsigned short*)(ws + off); off += xb_bytes;
  float* sumexp = (float*)(ws + off); off += (size_t)N * 4;
  float* Lrow   = (float*)(ws + off);

  hipMemsetAsync(sumexp, 0, N * sizeof(float), stream);
  prep_x<<<N / 4, 256, 0, stream>>>(x, xnb);

  dim3 grid(CT, N / 128);
  if (big) {
    prep_w<<<CP / 4, 256, 0, stream>>>(W, Wb);
    gemm_lse<true><<<grid, 256, 0, stream>>>(xnb, Wb, W, sumexp);
  } else {
    gemm_lse<false><<<grid, 256, 0, stream>>>(xnb, nullptr, W, sumexp);
  }
  finalize_rows<<<N / 4, 256, 0, stream>>>(x, W, label, sumexp, Lrow);
  reduce_loss<<<1, 256, 0, stream>>>(Lrow, out);
}